// Round 5
// baseline (218.697 us; speedup 1.0000x reference)
//
#include <hip/hip_runtime.h>
#include <cstdint>

#define IN_DIM 2048   // 2H
#define H_DIM  1024
#define BROWS  2048   // B*R
#define BATCH  64
#define ROUNDS 32

typedef __bf16 bf16x8 __attribute__((ext_vector_type(8)));
typedef float  f32x4  __attribute__((ext_vector_type(4)));
typedef unsigned short u16;
typedef u16 u16x8 __attribute__((ext_vector_type(8)));

// fp32 -> bf16 (RNE)
__device__ __forceinline__ u16 f2bf(float f) {
    unsigned int u = __float_as_uint(f);
    u += 0x7FFFu + ((u >> 16) & 1u);
    return (u16)(u >> 16);
}

// async global->LDS, 16 bytes/lane. LDS dest is wave-uniform base; HW adds lane*16.
__device__ __forceinline__ void async_ld16(const void* g, void* l) {
    __builtin_amdgcn_global_load_lds(
        (__attribute__((address_space(1))) void*)(uintptr_t)g,
        (__attribute__((address_space(3))) void*)(unsigned int)(uintptr_t)l,
        16, 0, 0);
}

// ---------------- 1. prep: input bf16 convert + fused weight transpose (UNCHANGED r3) -------
__global__ __launch_bounds__(256) void prep(
    const float* __restrict__ hist, const float* __restrict__ ques,
    u16* __restrict__ xh, u16* __restrict__ xq,
    const float* __restrict__ why, const float* __restrict__ whg,
    const float* __restrict__ wqy, const float* __restrict__ wqg,
    u16* __restrict__ oh, u16* __restrict__ oq)
{
    int idx = blockIdx.x;
    if (idx < 4096) {
        int i = idx * 256 + threadIdx.x;
        const float4* h4 = (const float4*)hist;
        const float4* q4 = (const float4*)ques;
        float4 a = h4[i], b = q4[i];
        ushort4 oa, ob;
        oa.x = f2bf(a.x); oa.y = f2bf(a.y); oa.z = f2bf(a.z); oa.w = f2bf(a.w);
        ob.x = f2bf(b.x); ob.y = f2bf(b.y); ob.z = f2bf(b.z); ob.w = f2bf(b.w);
        ((ushort4*)xh)[i] = oa;
        ((ushort4*)xq)[i] = ob;
        return;
    }
    int zz = idx - 4096;              // 0..1023
    int z  = zz >> 9;
    int rem = zz & 511;
    int bk = rem >> 5;                // 16 k-tiles of 128
    int bn = rem & 31;                // 32 n-tiles of 64
    const float* Y = z == 0 ? why : wqy;
    const float* G = z == 0 ? whg : wqg;
    u16* O = z == 0 ? oh : oq;
    int k0 = bk << 7, c0 = bn << 5, n0 = bn << 6;

    __shared__ float t[2][128][33];
    int tid = threadIdx.x;
    int row = tid >> 3, cg = (tid & 7) << 2;        // 32 rows x 8 float4-groups
    #pragma unroll
    for (int p = 0; p < 4; p++) {
        int k = row + 32 * p;
        float4 vy = *(const float4*)&Y[(size_t)(k0 + k) * H_DIM + c0 + cg];
        float4 vg = *(const float4*)&G[(size_t)(k0 + k) * H_DIM + c0 + cg];
        t[0][k][cg + 0] = vy.x; t[0][k][cg + 1] = vy.y;
        t[0][k][cg + 2] = vy.z; t[0][k][cg + 3] = vy.w;
        t[1][k][cg + 0] = vg.x; t[1][k][cg + 1] = vg.y;
        t[1][k][cg + 2] = vg.z; t[1][k][cg + 3] = vg.w;
    }
    __syncthreads();
    int j4 = tid >> 4, kg = tid & 15;               // 16 rows x 16 k-groups of 8
    #pragma unroll
    for (int p = 0; p < 4; p++) {
        int j = j4 + 16 * p;                        // 0..63 output row within tile
        int mat = (j >> 4) & 1;                     // 0 = Y (tanh), 1 = G (gate)
        int lc = ((j >> 5) << 4) | (j & 15);        // local source col 0..31
        u16x8 pk;
        #pragma unroll
        for (int e = 0; e < 8; e++)
            pk[e] = f2bf(t[mat][kg * 8 + e][lc]);
        *(u16x8*)&O[(size_t)(n0 + j) * IN_DIM + k0 + kg * 8] = pk;
    }
}

// ---------------- 2. bf16 MFMA GEMM, 128x128 tile, K-SPLIT x2, 16 waves/CU ------------------
// 512 blocks x 512 thr. Waves 0-3 compute K[0,1024), waves 4-7 K[1024,2048), each wave owns a
// 64x64 output quadrant (per-wave tile efficiency preserved -> LDS read bytes unchanged).
// LDS 64 KB/block => 2 blocks/CU co-resident = 16 waves/CU = 4 waves/SIMD (vs 2/SIMD in all
// prior 43-us variants): inter-wave overlap hides staging latency (m114). BK=32 dbuf per
// group, classic 2-phase __syncthreads schedule (stage next buffer, compute current).
// Epilogue: group 1 dumps fp32 acc to LDS (64 KB, reusing tile buffers), group 0 adds,
// applies tanh/leaky-relu, stores bf16.
__global__ __launch_bounds__(512, 4) void gemm_act(
    const u16* __restrict__ xh, const u16* __restrict__ xq,
    const u16* __restrict__ wth, const u16* __restrict__ wtq,
    const float* __restrict__ bhy, const float* __restrict__ bhg,
    const float* __restrict__ bqy, const float* __restrict__ bqg,
    u16* __restrict__ eh, u16* __restrict__ eq)
{
    int L = blockIdx.x;
    int cluster = L & 7;          // -> XCD via id%8
    int slot = L >> 3;            // 0..63 within cluster
    int z = cluster >> 2;
    int y = (cluster & 1) * 8 + (slot >> 3);          // 0..15 (M blocks of 128)
    int x = ((cluster >> 1) & 1) * 8 + (slot & 7);    // 0..15 (N blocks of 128)
    int m0 = y * 128, n0 = x * 128;

    const u16* A  = z == 0 ? xh : xq;
    const u16* Bt = z == 0 ? wth : wtq;
    const float* by = z == 0 ? bhy : bqy;
    const float* bg = z == 0 ? bhg : bqg;
    u16* E = z == 0 ? eh : eq;

    // 64 KB: [group][buf] A-seg (8 KB) x4 at 0..32KB, B-seg x4 at 32..64KB.
    // Within a seg: 128 rows x 4 chunks of 16B; phys chunk = logical ^ ((row>>1)&3).
    __shared__ __align__(16) u16 smem[32768];

    int tid = threadIdx.x;
    int wave = tid >> 6, lane = tid & 63;
    int g = wave >> 2;                 // K-group: 0 -> K[0,1024), 1 -> K[1024,2048)
    int qd = wave & 3;                 // output quadrant
    int lane15 = lane & 15, quad = lane >> 4;
    int wm = (qd >> 1) * 64, wn = (qd & 1) * 64;
    int tidg = tid & 255;              // thread id within group
    int kbase = g << 10;

    f32x4 acc[4][4];
    #pragma unroll
    for (int i = 0; i < 4; i++)
        #pragma unroll
        for (int j = 0; j < 4; j++) acc[i][j] = (f32x4){0.f, 0.f, 0.f, 0.f};

    // staging: per group 512 chunks (A) + 512 (B) over 256 threads = 2+2 slots of 16B
    int aoff[2], boff[2], cb[2];
    #pragma unroll
    for (int r2 = 0; r2 < 2; r2++) {
        int cs = r2 * 256 + tidg;
        int row = cs >> 2, p = cs & 3;
        int l = p ^ ((row >> 1) & 3);                 // logical chunk staged at phys p
        aoff[r2] = (m0 + row) * IN_DIM + kbase + l * 8;
        boff[r2] = (n0 + row) * IN_DIM + kbase + l * 8;
        cb[r2]   = (r2 * 256 + qd * 64) * 8;          // wave-uniform LDS u16 offset
    }

    #define STAGE(buf, ktrel)                                                                 \
        {                                                                                     \
            u16* sA = smem + ((g * 2 + (buf)) << 12);                                         \
            u16* sB = smem + 16384 + ((g * 2 + (buf)) << 12);                                 \
            _Pragma("unroll")                                                                 \
            for (int r2 = 0; r2 < 2; r2++) {                                                  \
                async_ld16(A  + (size_t)(aoff[r2] + (ktrel)), sA + cb[r2]);                   \
                async_ld16(Bt + (size_t)(boff[r2] + (ktrel)), sB + cb[r2]);                   \
            }                                                                                 \
        }

    bf16x8 af[4], bfv[4];

    #define DSREAD(buf)                                                                       \
        {                                                                                     \
            u16* sA = smem + ((g * 2 + (buf)) << 12);                                         \
            u16* sB = smem + 16384 + ((g * 2 + (buf)) << 12);                                 \
            _Pragma("unroll")                                                                 \
            for (int i = 0; i < 4; i++) {                                                     \
                int row = wm + i * 16 + lane15;                                               \
                int p = quad ^ ((row >> 1) & 3);                                              \
                af[i] = *(const bf16x8*)&sA[row * 32 + p * 8];                                \
                int rowb = wn + i * 16 + lane15;                                              \
                int pb = quad ^ ((rowb >> 1) & 3);                                            \
                bfv[i] = *(const bf16x8*)&sB[rowb * 32 + pb * 8];                             \
            }                                                                                 \
        }

    #define MFMA16()                                                                          \
        __builtin_amdgcn_s_setprio(1);                                                        \
        _Pragma("unroll")                                                                     \
        for (int i = 0; i < 4; i++)                                                           \
            _Pragma("unroll")                                                                 \
            for (int j = 0; j < 4; j++)                                                       \
                acc[i][j] = __builtin_amdgcn_mfma_f32_16x16x32_bf16(                          \
                    af[i], bfv[j], acc[i][j], 0, 0, 0);                                       \
        __builtin_amdgcn_s_setprio(0);

    // prologue: stage first buffer of this group's K-range
    STAGE(0, 0)
    __syncthreads();

    #pragma unroll 1
    for (int t2 = 0; t2 < 32; t2 += 2) {
        // tile t2 (buf0): issue next stage first so loads fly under MFMA
        if (t2 + 1 < 32) STAGE(1, (t2 + 1) * 32)
        DSREAD(0)
        MFMA16()
        __syncthreads();                       // drains buf1 stage; buf0 reads done
        // tile t2+1 (buf1)
        if (t2 + 2 < 32) STAGE(0, (t2 + 2) * 32)
        DSREAD(1)
        MFMA16()
        __syncthreads();                       // drains buf0 stage; buf1 reads done
    }
    #undef STAGE
    #undef DSREAD
    #undef MFMA16

    // ---- K-split reduction through LDS (64 KB free now) ----
    float* xch = (float*)smem;                 // 16384 floats; quadrant qd at qd*4096
    if (g == 1) {
        #pragma unroll
        for (int i = 0; i < 4; i++)
            #pragma unroll
            for (int j = 0; j < 4; j++)
                *(f32x4*)&xch[qd * 4096 + (i * 4 + j) * 256 + lane * 4] = acc[i][j];
    }
    __syncthreads();
    if (g == 0) {
        #pragma unroll
        for (int i = 0; i < 4; i++)
            #pragma unroll
            for (int j = 0; j < 4; j++) {
                f32x4 o = *(const f32x4*)&xch[qd * 4096 + (i * 4 + j) * 256 + lane * 4];
                acc[i][j].x += o.x; acc[i][j].y += o.y;
                acc[i][j].z += o.z; acc[i][j].w += o.w;
            }
        // epilogue: j-pairs (0,1),(2,3) = (tanh, gate) branches of the same H-col, same lane.
        int n0w = n0 + wn;
        #pragma unroll
        for (int jp = 0; jp < 2; jp++) {
            int hc = (n0w >> 1) + jp * 16 + lane15;
            float vy = by[hc], vg = bg[hc];
            #pragma unroll
            for (int i = 0; i < 4; i++) {
                #pragma unroll
                for (int r = 0; r < 4; r++) {
                    int row = m0 + wm + i * 16 + quad * 4 + r;
                    float y2 = tanhf(acc[i][2 * jp][r] + vy);
                    float gg = acc[i][2 * jp + 1][r] + vg;
                    E[(size_t)row * H_DIM + hc] = f2bf(y2 * (gg > 0.f ? gg : 0.01f * gg));
                }
            }
        }
    }
}

// ---------------- 3. scores + causal softmax + weighted hist sum (UNCHANGED r3) -------------
__global__ __launch_bounds__(256) void score_feat(
    const u16* __restrict__ eh, const u16* __restrict__ eq,
    const float* __restrict__ hist, const float* __restrict__ watt,
    const float* __restrict__ batt, float* __restrict__ out)
{
    int idx = blockIdx.x;
    int b = idx & 63, q = idx >> 6;
    int tid = threadIdx.x, wave = tid >> 6, lane = tid & 63;
    __shared__ float sw[32], swn[32];

    const u16* qe = eq + (size_t)(b * ROUNDS + q) * H_DIM;
    float uw[16], u2[16];
    #pragma unroll
    for (int c = 0; c < 2; c++) {
        uint4 pk = ((const uint4*)qe)[lane + 64 * c];     // 8 bf16
        float4 w0 = ((const float4*)watt)[(lane + 64 * c) * 2];
        float4 w1 = ((const float4*)watt)[(lane + 64 * c) * 2 + 1];
        unsigned int ws[4] = {pk.x, pk.y, pk.z, pk.w};
        float wf[8] = {w0.x, w0.y, w0.z, w0.w, w1.x, w1.y, w1.z, w1.w};
        #pragma unroll
        for (int e = 0; e < 4; e++) {
            float lo = __uint_as_float(ws[e] << 16);
            float hi = __uint_as_float(ws[e] & 0xFFFF0000u);
            uw[c * 8 + 2 * e]     = lo * wf[2 * e];
            u2[c * 8 + 2 * e]     = lo * lo;
            uw[c * 8 + 2 * e + 1] = hi * wf[2 * e + 1];
            u2[c * 8 + 2 * e + 1] = hi * hi;
        }
    }
    for (int h = wave; h <= q; h += 4) {
        const u16* he = eh + (size_t)(b * ROUNDS + h) * H_DIM;
        float num = 0.f, nrm = 0.f;
        #pragma unroll
        for (int c = 0; c < 2; c++) {
            uint4 pk = ((const uint4*)he)[lane + 64 * c];
            unsigned int vs[4] = {pk.x, pk.y, pk.z, pk.w};
            #pragma unroll
            for (int e = 0; e < 4; e++) {
                float lo = __uint_as_float(vs[e] << 16);
                float hi = __uint_as_float(vs[e] & 0xFFFF0000u);
                num += uw[c * 8 + 2 * e] * lo + uw[c * 8 + 2 * e + 1] * hi;
                nrm += u2[c * 8 + 2 * e] * lo * lo + u2[c * 8 + 2 * e + 1] * hi * hi;
            }
        }
        #pragma unroll
        for (int off = 32; off > 0; off >>= 1) {
            num += __shfl_down(num, off);
            nrm += __shfl_down(nrm, off);
        }
        if (lane == 0)
            sw[h] = num / fmaxf(sqrtf(nrm), 1e-12f) + batt[0];
    }
    __syncthreads();
    if (tid < 64) {
        int h = lane & 31;
        bool v = (h <= q);
        float s = v ? sw[h] : -1e30f;
        float mx = s;
        #pragma unroll
        for (int off = 16; off > 0; off >>= 1)
            mx = fmaxf(mx, __shfl_xor(mx, off));
        float e = v ? expf(s - mx) : 0.f;
        float zs = e;
        #pragma unroll
        for (int off = 16; off > 0; off >>= 1)
            zs += __shfl_xor(zs, off);
        if (v && lane < 32) swn[h] = e / zs;
    }
    __syncthreads();
    const float4* hb = (const float4*)(hist + (size_t)b * ROUNDS * IN_DIM);
    float4* ob = (float4*)(out + (size_t)(b * ROUNDS + q) * IN_DIM);
    #pragma unroll
    for (int d0 = 0; d0 < 2; d0++) {
        int d = tid + d0 * 256;          // < 512 float4s
        float4 a = {0.f, 0.f, 0.f, 0.f};
        for (int h = 0; h <= q; h++) {
            float w = swn[h];
            float4 x = hb[h * 512 + d];
            a.x += w * x.x; a.y += w * x.y; a.z += w * x.z; a.w += w * x.w;
        }
        ob[d] = a;
    }
}

extern "C" void kernel_launch(void* const* d_in, const int* in_sizes, int n_in,
                              void* d_out, int out_size, void* d_ws, size_t ws_size,
                              hipStream_t stream) {
    const float* hist = (const float*)d_in[0];
    const float* ques = (const float*)d_in[1];
    const float* Why  = (const float*)d_in[2];
    const float* bhy  = (const float*)d_in[3];
    const float* Whg  = (const float*)d_in[4];
    const float* bhg  = (const float*)d_in[5];
    const float* Wqy  = (const float*)d_in[6];
    const float* bqy  = (const float*)d_in[7];
    const float* Wqg  = (const float*)d_in[8];
    const float* bqg  = (const float*)d_in[9];
    const float* watt = (const float*)d_in[10];
    const float* batt = (const float*)d_in[11];
    float* out = (float*)d_out;

    // workspace (~42 MB)
    char* w = (char*)d_ws;
    u16* Xh  = (u16*)w;                               // [2048,2048] bf16
    u16* Xq  = Xh  + (size_t)BROWS * IN_DIM;
    u16* WtH = Xq  + (size_t)BROWS * IN_DIM;          // [2048,2048] bf16 fused-interleaved
    u16* WtQ = WtH + (size_t)IN_DIM * IN_DIM;
    u16* Eh  = WtQ + (size_t)IN_DIM * IN_DIM;         // [2048,1024] bf16
    u16* Eq  = Eh  + (size_t)BROWS * H_DIM;

    prep<<<5120, 256, 0, stream>>>(hist, ques, Xh, Xq, Why, Whg, Wqy, Wqg, WtH, WtQ);
    gemm_act<<<512, 512, 0, stream>>>(Xh, Xq, WtH, WtQ, bhy, bhg, bqy, bqg, Eh, Eq);
    score_feat<<<2048, 256, 0, stream>>>(Eh, Eq, hist, watt, batt, out);
}

// Round 6
// 196.758 us; speedup vs baseline: 1.1115x; 1.1115x over previous
//
#include <hip/hip_runtime.h>
#include <cstdint>

#define IN_DIM 2048   // 2H
#define H_DIM  1024
#define BROWS  2048   // B*R
#define BATCH  64
#define ROUNDS 32

typedef __bf16 bf16x8 __attribute__((ext_vector_type(8)));
typedef float  f32x4  __attribute__((ext_vector_type(4)));
typedef unsigned short u16;
typedef u16 u16x8 __attribute__((ext_vector_type(8)));

// fp32 -> bf16 (RNE)
__device__ __forceinline__ u16 f2bf(float f) {
    unsigned int u = __float_as_uint(f);
    u += 0x7FFFu + ((u >> 16) & 1u);
    return (u16)(u >> 16);
}

// async global->LDS, 16 bytes/lane. LDS dest is wave-uniform base; HW adds lane*16.
__device__ __forceinline__ void async_ld16(const void* g, void* l) {
    __builtin_amdgcn_global_load_lds(
        (__attribute__((address_space(1))) void*)(uintptr_t)g,
        (__attribute__((address_space(3))) void*)(unsigned int)(uintptr_t)l,
        16, 0, 0);
}

// ---------------- 1. prep: input bf16 convert + fused weight transpose (UNCHANGED r3) -------
__global__ __launch_bounds__(256) void prep(
    const float* __restrict__ hist, const float* __restrict__ ques,
    u16* __restrict__ xh, u16* __restrict__ xq,
    const float* __restrict__ why, const float* __restrict__ whg,
    const float* __restrict__ wqy, const float* __restrict__ wqg,
    u16* __restrict__ oh, u16* __restrict__ oq)
{
    int idx = blockIdx.x;
    if (idx < 4096) {
        int i = idx * 256 + threadIdx.x;
        const float4* h4 = (const float4*)hist;
        const float4* q4 = (const float4*)ques;
        float4 a = h4[i], b = q4[i];
        ushort4 oa, ob;
        oa.x = f2bf(a.x); oa.y = f2bf(a.y); oa.z = f2bf(a.z); oa.w = f2bf(a.w);
        ob.x = f2bf(b.x); ob.y = f2bf(b.y); ob.z = f2bf(b.z); ob.w = f2bf(b.w);
        ((ushort4*)xh)[i] = oa;
        ((ushort4*)xq)[i] = ob;
        return;
    }
    int zz = idx - 4096;              // 0..1023
    int z  = zz >> 9;
    int rem = zz & 511;
    int bk = rem >> 5;                // 16 k-tiles of 128
    int bn = rem & 31;                // 32 n-tiles of 64
    const float* Y = z == 0 ? why : wqy;
    const float* G = z == 0 ? whg : wqg;
    u16* O = z == 0 ? oh : oq;
    int k0 = bk << 7, c0 = bn << 5, n0 = bn << 6;

    __shared__ float t[2][128][33];
    int tid = threadIdx.x;
    int row = tid >> 3, cg = (tid & 7) << 2;        // 32 rows x 8 float4-groups
    #pragma unroll
    for (int p = 0; p < 4; p++) {
        int k = row + 32 * p;
        float4 vy = *(const float4*)&Y[(size_t)(k0 + k) * H_DIM + c0 + cg];
        float4 vg = *(const float4*)&G[(size_t)(k0 + k) * H_DIM + c0 + cg];
        t[0][k][cg + 0] = vy.x; t[0][k][cg + 1] = vy.y;
        t[0][k][cg + 2] = vy.z; t[0][k][cg + 3] = vy.w;
        t[1][k][cg + 0] = vg.x; t[1][k][cg + 1] = vg.y;
        t[1][k][cg + 2] = vg.z; t[1][k][cg + 3] = vg.w;
    }
    __syncthreads();
    int j4 = tid >> 4, kg = tid & 15;               // 16 rows x 16 k-groups of 8
    #pragma unroll
    for (int p = 0; p < 4; p++) {
        int j = j4 + 16 * p;                        // 0..63 output row within tile
        int mat = (j >> 4) & 1;                     // 0 = Y (tanh), 1 = G (gate)
        int lc = ((j >> 5) << 4) | (j & 15);        // local source col 0..31
        u16x8 pk;
        #pragma unroll
        for (int e = 0; e < 8; e++)
            pk[e] = f2bf(t[mat][kg * 8 + e][lc]);
        *(u16x8*)&O[(size_t)(n0 + j) * IN_DIM + k0 + kg * 8] = pk;
    }
}

// ---------------- 2. bf16 MFMA GEMM, 128x128 tile, K-SPLIT x2, 16 waves/CU ------------------
// Identical to r5 EXCEPT __launch_bounds__(512, 2): r5's (512,4) capped VGPR at 64 -> acc
// spilled to scratch (WRITE_SIZE 8->41 MB). (512,2) caps at 128 (r1/r2 compiled to 108),
// LDS 64 KB still co-resides 2 blocks/CU = 16 waves/CU = 4 waves/SIMD. Clean occupancy A/B.
__global__ __launch_bounds__(512, 2) void gemm_act(
    const u16* __restrict__ xh, const u16* __restrict__ xq,
    const u16* __restrict__ wth, const u16* __restrict__ wtq,
    const float* __restrict__ bhy, const float* __restrict__ bhg,
    const float* __restrict__ bqy, const float* __restrict__ bqg,
    u16* __restrict__ eh, u16* __restrict__ eq)
{
    int L = blockIdx.x;
    int cluster = L & 7;          // -> XCD via id%8
    int slot = L >> 3;            // 0..63 within cluster
    int z = cluster >> 2;
    int y = (cluster & 1) * 8 + (slot >> 3);          // 0..15 (M blocks of 128)
    int x = ((cluster >> 1) & 1) * 8 + (slot & 7);    // 0..15 (N blocks of 128)
    int m0 = y * 128, n0 = x * 128;

    const u16* A  = z == 0 ? xh : xq;
    const u16* Bt = z == 0 ? wth : wtq;
    const float* by = z == 0 ? bhy : bqy;
    const float* bg = z == 0 ? bhg : bqg;
    u16* E = z == 0 ? eh : eq;

    // 64 KB: [group][buf] A-seg (8 KB) x4 at 0..32KB, B-seg x4 at 32..64KB.
    // Within a seg: 128 rows x 4 chunks of 16B; phys chunk = logical ^ ((row>>1)&3).
    __shared__ __align__(16) u16 smem[32768];

    int tid = threadIdx.x;
    int wave = tid >> 6, lane = tid & 63;
    int g = wave >> 2;                 // K-group: 0 -> K[0,1024), 1 -> K[1024,2048)
    int qd = wave & 3;                 // output quadrant
    int lane15 = lane & 15, quad = lane >> 4;
    int wm = (qd >> 1) * 64, wn = (qd & 1) * 64;
    int tidg = tid & 255;              // thread id within group
    int kbase = g << 10;

    f32x4 acc[4][4];
    #pragma unroll
    for (int i = 0; i < 4; i++)
        #pragma unroll
        for (int j = 0; j < 4; j++) acc[i][j] = (f32x4){0.f, 0.f, 0.f, 0.f};

    // staging: per group 512 chunks (A) + 512 (B) over 256 threads = 2+2 slots of 16B
    int aoff[2], boff[2], cb[2];
    #pragma unroll
    for (int r2 = 0; r2 < 2; r2++) {
        int cs = r2 * 256 + tidg;
        int row = cs >> 2, p = cs & 3;
        int l = p ^ ((row >> 1) & 3);                 // logical chunk staged at phys p
        aoff[r2] = (m0 + row) * IN_DIM + kbase + l * 8;
        boff[r2] = (n0 + row) * IN_DIM + kbase + l * 8;
        cb[r2]   = (r2 * 256 + qd * 64) * 8;          // wave-uniform LDS u16 offset
    }

    #define STAGE(buf, ktrel)                                                                 \
        {                                                                                     \
            u16* sA = smem + ((g * 2 + (buf)) << 12);                                         \
            u16* sB = smem + 16384 + ((g * 2 + (buf)) << 12);                                 \
            _Pragma("unroll")                                                                 \
            for (int r2 = 0; r2 < 2; r2++) {                                                  \
                async_ld16(A  + (size_t)(aoff[r2] + (ktrel)), sA + cb[r2]);                   \
                async_ld16(Bt + (size_t)(boff[r2] + (ktrel)), sB + cb[r2]);                   \
            }                                                                                 \
        }

    bf16x8 af[4], bfv[4];

    #define DSREAD(buf)                                                                       \
        {                                                                                     \
            u16* sA = smem + ((g * 2 + (buf)) << 12);                                         \
            u16* sB = smem + 16384 + ((g * 2 + (buf)) << 12);                                 \
            _Pragma("unroll")                                                                 \
            for (int i = 0; i < 4; i++) {                                                     \
                int row = wm + i * 16 + lane15;                                               \
                int p = quad ^ ((row >> 1) & 3);                                              \
                af[i] = *(const bf16x8*)&sA[row * 32 + p * 8];                                \
                int rowb = wn + i * 16 + lane15;                                              \
                int pb = quad ^ ((rowb >> 1) & 3);                                            \
                bfv[i] = *(const bf16x8*)&sB[rowb * 32 + pb * 8];                             \
            }                                                                                 \
        }

    #define MFMA16()                                                                          \
        __builtin_amdgcn_s_setprio(1);                                                        \
        _Pragma("unroll")                                                                     \
        for (int i = 0; i < 4; i++)                                                           \
            _Pragma("unroll")                                                                 \
            for (int j = 0; j < 4; j++)                                                       \
                acc[i][j] = __builtin_amdgcn_mfma_f32_16x16x32_bf16(                          \
                    af[i], bfv[j], acc[i][j], 0, 0, 0);                                       \
        __builtin_amdgcn_s_setprio(0);

    // prologue: stage first buffer of this group's K-range
    STAGE(0, 0)
    __syncthreads();

    #pragma unroll 1
    for (int t2 = 0; t2 < 32; t2 += 2) {
        // tile t2 (buf0): issue next stage first so loads fly under MFMA
        if (t2 + 1 < 32) STAGE(1, (t2 + 1) * 32)
        DSREAD(0)
        MFMA16()
        __syncthreads();                       // drains buf1 stage; buf0 reads done
        // tile t2+1 (buf1)
        if (t2 + 2 < 32) STAGE(0, (t2 + 2) * 32)
        DSREAD(1)
        MFMA16()
        __syncthreads();                       // drains buf0 stage; buf1 reads done
    }
    #undef STAGE
    #undef DSREAD
    #undef MFMA16

    // ---- K-split reduction through LDS (64 KB free now) ----
    float* xch = (float*)smem;                 // 16384 floats; quadrant qd at qd*4096
    if (g == 1) {
        #pragma unroll
        for (int i = 0; i < 4; i++)
            #pragma unroll
            for (int j = 0; j < 4; j++)
                *(f32x4*)&xch[qd * 4096 + (i * 4 + j) * 256 + lane * 4] = acc[i][j];
    }
    __syncthreads();
    if (g == 0) {
        #pragma unroll
        for (int i = 0; i < 4; i++)
            #pragma unroll
            for (int j = 0; j < 4; j++) {
                f32x4 o = *(const f32x4*)&xch[qd * 4096 + (i * 4 + j) * 256 + lane * 4];
                acc[i][j].x += o.x; acc[i][j].y += o.y;
                acc[i][j].z += o.z; acc[i][j].w += o.w;
            }
        // epilogue: j-pairs (0,1),(2,3) = (tanh, gate) branches of the same H-col, same lane.
        int n0w = n0 + wn;
        #pragma unroll
        for (int jp = 0; jp < 2; jp++) {
            int hc = (n0w >> 1) + jp * 16 + lane15;
            float vy = by[hc], vg = bg[hc];
            #pragma unroll
            for (int i = 0; i < 4; i++) {
                #pragma unroll
                for (int r = 0; r < 4; r++) {
                    int row = m0 + wm + i * 16 + quad * 4 + r;
                    float y2 = tanhf(acc[i][2 * jp][r] + vy);
                    float gg = acc[i][2 * jp + 1][r] + vg;
                    E[(size_t)row * H_DIM + hc] = f2bf(y2 * (gg > 0.f ? gg : 0.01f * gg));
                }
            }
        }
    }
}

// ---------------- 3. scores + causal softmax + weighted hist sum (UNCHANGED r3) -------------
__global__ __launch_bounds__(256) void score_feat(
    const u16* __restrict__ eh, const u16* __restrict__ eq,
    const float* __restrict__ hist, const float* __restrict__ watt,
    const float* __restrict__ batt, float* __restrict__ out)
{
    int idx = blockIdx.x;
    int b = idx & 63, q = idx >> 6;
    int tid = threadIdx.x, wave = tid >> 6, lane = tid & 63;
    __shared__ float sw[32], swn[32];

    const u16* qe = eq + (size_t)(b * ROUNDS + q) * H_DIM;
    float uw[16], u2[16];
    #pragma unroll
    for (int c = 0; c < 2; c++) {
        uint4 pk = ((const uint4*)qe)[lane + 64 * c];     // 8 bf16
        float4 w0 = ((const float4*)watt)[(lane + 64 * c) * 2];
        float4 w1 = ((const float4*)watt)[(lane + 64 * c) * 2 + 1];
        unsigned int ws[4] = {pk.x, pk.y, pk.z, pk.w};
        float wf[8] = {w0.x, w0.y, w0.z, w0.w, w1.x, w1.y, w1.z, w1.w};
        #pragma unroll
        for (int e = 0; e < 4; e++) {
            float lo = __uint_as_float(ws[e] << 16);
            float hi = __uint_as_float(ws[e] & 0xFFFF0000u);
            uw[c * 8 + 2 * e]     = lo * wf[2 * e];
            u2[c * 8 + 2 * e]     = lo * lo;
            uw[c * 8 + 2 * e + 1] = hi * wf[2 * e + 1];
            u2[c * 8 + 2 * e + 1] = hi * hi;
        }
    }
    for (int h = wave; h <= q; h += 4) {
        const u16* he = eh + (size_t)(b * ROUNDS + h) * H_DIM;
        float num = 0.f, nrm = 0.f;
        #pragma unroll
        for (int c = 0; c < 2; c++) {
            uint4 pk = ((const uint4*)he)[lane + 64 * c];
            unsigned int vs[4] = {pk.x, pk.y, pk.z, pk.w};
            #pragma unroll
            for (int e = 0; e < 4; e++) {
                float lo = __uint_as_float(vs[e] << 16);
                float hi = __uint_as_float(vs[e] & 0xFFFF0000u);
                num += uw[c * 8 + 2 * e] * lo + uw[c * 8 + 2 * e + 1] * hi;
                nrm += u2[c * 8 + 2 * e] * lo * lo + u2[c * 8 + 2 * e + 1] * hi * hi;
            }
        }
        #pragma unroll
        for (int off = 32; off > 0; off >>= 1) {
            num += __shfl_down(num, off);
            nrm += __shfl_down(nrm, off);
        }
        if (lane == 0)
            sw[h] = num / fmaxf(sqrtf(nrm), 1e-12f) + batt[0];
    }
    __syncthreads();
    if (tid < 64) {
        int h = lane & 31;
        bool v = (h <= q);
        float s = v ? sw[h] : -1e30f;
        float mx = s;
        #pragma unroll
        for (int off = 16; off > 0; off >>= 1)
            mx = fmaxf(mx, __shfl_xor(mx, off));
        float e = v ? expf(s - mx) : 0.f;
        float zs = e;
        #pragma unroll
        for (int off = 16; off > 0; off >>= 1)
            zs += __shfl_xor(zs, off);
        if (v && lane < 32) swn[h] = e / zs;
    }
    __syncthreads();
    const float4* hb = (const float4*)(hist + (size_t)b * ROUNDS * IN_DIM);
    float4* ob = (float4*)(out + (size_t)(b * ROUNDS + q) * IN_DIM);
    #pragma unroll
    for (int d0 = 0; d0 < 2; d0++) {
        int d = tid + d0 * 256;          // < 512 float4s
        float4 a = {0.f, 0.f, 0.f, 0.f};
        for (int h = 0; h <= q; h++) {
            float w = swn[h];
            float4 x = hb[h * 512 + d];
            a.x += w * x.x; a.y += w * x.y; a.z += w * x.z; a.w += w * x.w;
        }
        ob[d] = a;
    }
}

extern "C" void kernel_launch(void* const* d_in, const int* in_sizes, int n_in,
                              void* d_out, int out_size, void* d_ws, size_t ws_size,
                              hipStream_t stream) {
    const float* hist = (const float*)d_in[0];
    const float* ques = (const float*)d_in[1];
    const float* Why  = (const float*)d_in[2];
    const float* bhy  = (const float*)d_in[3];
    const float* Whg  = (const float*)d_in[4];
    const float* bhg  = (const float*)d_in[5];
    const float* Wqy  = (const float*)d_in[6];
    const float* bqy  = (const float*)d_in[7];
    const float* Wqg  = (const float*)d_in[8];
    const float* bqg  = (const float*)d_in[9];
    const float* watt = (const float*)d_in[10];
    const float* batt = (const float*)d_in[11];
    float* out = (float*)d_out;

    // workspace (~42 MB)
    char* w = (char*)d_ws;
    u16* Xh  = (u16*)w;                               // [2048,2048] bf16
    u16* Xq  = Xh  + (size_t)BROWS * IN_DIM;
    u16* WtH = Xq  + (size_t)BROWS * IN_DIM;          // [2048,2048] bf16 fused-interleaved
    u16* WtQ = WtH + (size_t)IN_DIM * IN_DIM;
    u16* Eh  = WtQ + (size_t)IN_DIM * IN_DIM;         // [2048,1024] bf16
    u16* Eq  = Eh  + (size_t)BROWS * H_DIM;

    prep<<<5120, 256, 0, stream>>>(hist, ques, Xh, Xq, Why, Whg, Wqy, Wqg, WtH, WtQ);
    gemm_act<<<512, 512, 0, stream>>>(Xh, Xq, WtH, WtQ, bhy, bhg, bqy, bqg, Eh, Eq);
    score_feat<<<2048, 256, 0, stream>>>(Eh, Eq, hist, watt, batt, out);
}

// Round 7
// 181.650 us; speedup vs baseline: 1.2039x; 1.0832x over previous
//
#include <hip/hip_runtime.h>
#include <cstdint>

#define IN_DIM 2048   // 2H
#define H_DIM  1024
#define BROWS  2048   // B*R
#define BATCH  64
#define ROUNDS 32

typedef __bf16 bf16x8 __attribute__((ext_vector_type(8)));
typedef float  f32x4  __attribute__((ext_vector_type(4)));
typedef unsigned short u16;
typedef u16 u16x8 __attribute__((ext_vector_type(8)));

// fp32 -> bf16 (RNE)
__device__ __forceinline__ u16 f2bf(float f) {
    unsigned int u = __float_as_uint(f);
    u += 0x7FFFu + ((u >> 16) & 1u);
    return (u16)(u >> 16);
}

// async global->LDS, 16 bytes/lane. LDS dest is wave-uniform base; HW adds lane*16.
__device__ __forceinline__ void async_ld16(const void* g, void* l) {
    __builtin_amdgcn_global_load_lds(
        (__attribute__((address_space(1))) void*)(uintptr_t)g,
        (__attribute__((address_space(3))) void*)(unsigned int)(uintptr_t)l,
        16, 0, 0);
}

#define BAR()    asm volatile("s_barrier" ::: "memory")
#define VMCNT6() asm volatile("s_waitcnt vmcnt(6)" ::: "memory")
#define VMCNT3() asm volatile("s_waitcnt vmcnt(3)" ::: "memory")
#define VMCNT0() asm volatile("s_waitcnt vmcnt(0)" ::: "memory")

// ---------------- 1. prep: input bf16 convert + fused weight transpose (UNCHANGED r3) -------
__global__ __launch_bounds__(256) void prep(
    const float* __restrict__ hist, const float* __restrict__ ques,
    u16* __restrict__ xh, u16* __restrict__ xq,
    const float* __restrict__ why, const float* __restrict__ whg,
    const float* __restrict__ wqy, const float* __restrict__ wqg,
    u16* __restrict__ oh, u16* __restrict__ oq)
{
    int idx = blockIdx.x;
    if (idx < 4096) {
        int i = idx * 256 + threadIdx.x;
        const float4* h4 = (const float4*)hist;
        const float4* q4 = (const float4*)ques;
        float4 a = h4[i], b = q4[i];
        ushort4 oa, ob;
        oa.x = f2bf(a.x); oa.y = f2bf(a.y); oa.z = f2bf(a.z); oa.w = f2bf(a.w);
        ob.x = f2bf(b.x); ob.y = f2bf(b.y); ob.z = f2bf(b.z); ob.w = f2bf(b.w);
        ((ushort4*)xh)[i] = oa;
        ((ushort4*)xq)[i] = ob;
        return;
    }
    int zz = idx - 4096;              // 0..1023
    int z  = zz >> 9;
    int rem = zz & 511;
    int bk = rem >> 5;                // 16 k-tiles of 128
    int bn = rem & 31;                // 32 n-tiles of 64
    const float* Y = z == 0 ? why : wqy;
    const float* G = z == 0 ? whg : wqg;
    u16* O = z == 0 ? oh : oq;
    int k0 = bk << 7, c0 = bn << 5, n0 = bn << 6;

    __shared__ float t[2][128][33];
    int tid = threadIdx.x;
    int row = tid >> 3, cg = (tid & 7) << 2;        // 32 rows x 8 float4-groups
    #pragma unroll
    for (int p = 0; p < 4; p++) {
        int k = row + 32 * p;
        float4 vy = *(const float4*)&Y[(size_t)(k0 + k) * H_DIM + c0 + cg];
        float4 vg = *(const float4*)&G[(size_t)(k0 + k) * H_DIM + c0 + cg];
        t[0][k][cg + 0] = vy.x; t[0][k][cg + 1] = vy.y;
        t[0][k][cg + 2] = vy.z; t[0][k][cg + 3] = vy.w;
        t[1][k][cg + 0] = vg.x; t[1][k][cg + 1] = vg.y;
        t[1][k][cg + 2] = vg.z; t[1][k][cg + 3] = vg.w;
    }
    __syncthreads();
    int j4 = tid >> 4, kg = tid & 15;               // 16 rows x 16 k-groups of 8
    #pragma unroll
    for (int p = 0; p < 4; p++) {
        int j = j4 + 16 * p;                        // 0..63 output row within tile
        int mat = (j >> 4) & 1;                     // 0 = Y (tanh), 1 = G (gate)
        int lc = ((j >> 5) << 4) | (j & 15);        // local source col 0..31
        u16x8 pk;
        #pragma unroll
        for (int e = 0; e < 8; e++)
            pk[e] = f2bf(t[mat][kg * 8 + e][lc]);
        *(u16x8*)&O[(size_t)(n0 + j) * IN_DIM + k0 + kg * 8] = pk;
    }
}

// ---------------- 2. bf16 MFMA GEMM, BM=256 x BN=128, BK=32, QUAD-buffer depth-3 ------------
// 256 blocks x 512 thr, 96 KB LDS (4 bufs x 24 KB). Depth-3 prefetch: while computing tile t,
// tiles t+1..t+3 (9 loads/thread) are in flight; consume-wait vmcnt(6) sits AFTER the MFMA
// cluster. All prior variants had depth <=1.5 and tied at dur = unique-bytes/~1 TB/s; this
// triples outstanding staging per wave at identical bytes/tiles/occupancy.
// LDS layout per buf: A 8192 u16 then B 4096 u16. Row-pair swizzle: 8 chunks of 16B per
// row-pair; phys8 = ((row&1)*4 + kchunk) ^ ((row>>1)&7)  -> ds_read 2-way conflicts (free).
__global__ __launch_bounds__(512, 1) void gemm_act(
    const u16* __restrict__ xh, const u16* __restrict__ xq,
    const u16* __restrict__ wth, const u16* __restrict__ wtq,
    const float* __restrict__ bhy, const float* __restrict__ bhg,
    const float* __restrict__ bqy, const float* __restrict__ bqg,
    u16* __restrict__ eh, u16* __restrict__ eq)
{
    int L = blockIdx.x;
    int cluster = L & 7;          // -> XCD via id%8
    int slot = L >> 3;            // 0..31 within cluster
    int z = cluster >> 2;
    int y = (cluster & 1) * 4 + (slot >> 3);          // 0..7  (M blocks of 256)
    int x = ((cluster >> 1) & 1) * 8 + (slot & 7);    // 0..15 (N blocks of 128)
    int m0 = y * 256, n0 = x * 128;

    const u16* A  = z == 0 ? xh : xq;
    const u16* Bt = z == 0 ? wth : wtq;
    const float* by = z == 0 ? bhy : bqy;
    const float* bg = z == 0 ? bhg : bqg;
    u16* E = z == 0 ? eh : eq;

    __shared__ __align__(16) u16 smem[49152];   // 96 KB

    int tid = threadIdx.x;
    int wave = tid >> 6, lane = tid & 63;
    int lane15 = lane & 15, quad = lane >> 4;
    int wm = (wave & 3) * 64;     // 4 waves along M
    int wn = (wave >> 2) * 64;    // 2 waves along N

    f32x4 acc[4][4];
    #pragma unroll
    for (int i = 0; i < 4; i++)
        #pragma unroll
        for (int j = 0; j < 4; j++) acc[i][j] = (f32x4){0.f, 0.f, 0.f, 0.f};

    // staging: per tile A = 256 rows x 4 chunks = 1024 chunks -> 2 slots; B = 512 -> 1 slot.
    // LDS is linear in chunk index cs; the SOURCE is pre-swizzled so that phys slot p8 of
    // row-pair row2 holds logical chunk l8 = p8 ^ (row2&7)  (l8: row-parity l8>>2, kchunk l8&3).
    int aoff[2], acb[2], boff, bcb;
    #pragma unroll
    for (int r2 = 0; r2 < 2; r2++) {
        int cs = r2 * 512 + tid;
        int row2 = cs >> 3, p8 = cs & 7;
        int l8 = p8 ^ (row2 & 7);
        aoff[r2] = (m0 + row2 * 2 + (l8 >> 2)) * IN_DIM + (l8 & 3) * 8;
        acb[r2]  = (r2 * 512 + wave * 64) * 8;          // wave-uniform u16 offset
    }
    {
        int row2 = tid >> 3, p8 = tid & 7;
        int l8 = p8 ^ (row2 & 7);
        boff = (n0 + row2 * 2 + (l8 >> 2)) * IN_DIM + (l8 & 3) * 8;
        bcb  = (wave * 64) * 8;
    }

    #define STAGE(buf, kt)                                                                    \
        {                                                                                     \
            u16* sA = smem + (buf) * 12288;                                                   \
            u16* sB = sA + 8192;                                                              \
            async_ld16(A  + (size_t)(aoff[0] + (kt)), sA + acb[0]);                           \
            async_ld16(A  + (size_t)(aoff[1] + (kt)), sA + acb[1]);                           \
            async_ld16(Bt + (size_t)(boff    + (kt)), sB + bcb);                              \
        }

    bf16x8 af[4], bfv[4];

    #define DSREAD(buf)                                                                       \
        {                                                                                     \
            const u16* sA = smem + (buf) * 12288;                                             \
            const u16* sB = sA + 8192;                                                        \
            _Pragma("unroll")                                                                 \
            for (int i = 0; i < 4; i++) {                                                     \
                int row = wm + i * 16 + lane15;                                               \
                int r2w = row >> 1;                                                           \
                int p8 = (((row & 1) << 2) | quad) ^ (r2w & 7);                               \
                af[i] = *(const bf16x8*)&sA[r2w * 64 + p8 * 8];                               \
                int rowb = wn + i * 16 + lane15;                                              \
                int r2b = rowb >> 1;                                                          \
                int pb8 = (((rowb & 1) << 2) | quad) ^ (r2b & 7);                             \
                bfv[i] = *(const bf16x8*)&sB[r2b * 64 + pb8 * 8];                             \
            }                                                                                 \
        }

    #define MFMA16()                                                                          \
        __builtin_amdgcn_s_setprio(1);                                                        \
        _Pragma("unroll")                                                                     \
        for (int i = 0; i < 4; i++)                                                           \
            _Pragma("unroll")                                                                 \
            for (int j = 0; j < 4; j++)                                                       \
                acc[i][j] = __builtin_amdgcn_mfma_f32_16x16x32_bf16(                          \
                    af[i], bfv[j], acc[i][j], 0, 0, 0);                                       \
        __builtin_amdgcn_s_setprio(0);

    // prologue: stage tiles 0,1,2 (9 loads); tile 0 ready when only 6 newest remain
    STAGE(0, 0)
    STAGE(1, 32)
    STAGE(2, 64)
    VMCNT6(); BAR();

    #pragma unroll 1
    for (int t = 0; t < 64; ++t) {
        int buf = t & 3;
        DSREAD(buf)                                    // frags for tile t
        if (t <= 60) STAGE((t + 3) & 3, (t + 3) * 32)  // overwrites buf (t-1)&3: freed last iter
        MFMA16()                                       // drains this wave's ds_reads (lgkm deps)
        if (t <= 60)      { VMCNT6(); }                // tile t+1 ready (t+2,t+3 stay in flight)
        else if (t == 61) { VMCNT3(); }
        else if (t == 62) { VMCNT0(); }
        if (t < 63) BAR();
    }
    #undef STAGE
    #undef DSREAD
    #undef MFMA16

    // epilogue: j-pairs (0,1),(2,3) = (tanh, gate) branches of the same H-col, same lane.
    int n0w = n0 + wn;
    #pragma unroll
    for (int jp = 0; jp < 2; jp++) {
        int hc = (n0w >> 1) + jp * 16 + lane15;
        float vy = by[hc], vg = bg[hc];
        #pragma unroll
        for (int i = 0; i < 4; i++) {
            #pragma unroll
            for (int r = 0; r < 4; r++) {
                int row = m0 + wm + i * 16 + quad * 4 + r;
                float y2 = tanhf(acc[i][2 * jp][r] + vy);
                float g = acc[i][2 * jp + 1][r] + vg;
                E[(size_t)row * H_DIM + hc] = f2bf(y2 * (g > 0.f ? g : 0.01f * g));
            }
        }
    }
}

// ---------------- 3. scores + causal softmax + weighted hist sum (UNCHANGED r3) -------------
__global__ __launch_bounds__(256) void score_feat(
    const u16* __restrict__ eh, const u16* __restrict__ eq,
    const float* __restrict__ hist, const float* __restrict__ watt,
    const float* __restrict__ batt, float* __restrict__ out)
{
    int idx = blockIdx.x;
    int b = idx & 63, q = idx >> 6;
    int tid = threadIdx.x, wave = tid >> 6, lane = tid & 63;
    __shared__ float sw[32], swn[32];

    const u16* qe = eq + (size_t)(b * ROUNDS + q) * H_DIM;
    float uw[16], u2[16];
    #pragma unroll
    for (int c = 0; c < 2; c++) {
        uint4 pk = ((const uint4*)qe)[lane + 64 * c];     // 8 bf16
        float4 w0 = ((const float4*)watt)[(lane + 64 * c) * 2];
        float4 w1 = ((const float4*)watt)[(lane + 64 * c) * 2 + 1];
        unsigned int ws[4] = {pk.x, pk.y, pk.z, pk.w};
        float wf[8] = {w0.x, w0.y, w0.z, w0.w, w1.x, w1.y, w1.z, w1.w};
        #pragma unroll
        for (int e = 0; e < 4; e++) {
            float lo = __uint_as_float(ws[e] << 16);
            float hi = __uint_as_float(ws[e] & 0xFFFF0000u);
            uw[c * 8 + 2 * e]     = lo * wf[2 * e];
            u2[c * 8 + 2 * e]     = lo * lo;
            uw[c * 8 + 2 * e + 1] = hi * wf[2 * e + 1];
            u2[c * 8 + 2 * e + 1] = hi * hi;
        }
    }
    for (int h = wave; h <= q; h += 4) {
        const u16* he = eh + (size_t)(b * ROUNDS + h) * H_DIM;
        float num = 0.f, nrm = 0.f;
        #pragma unroll
        for (int c = 0; c < 2; c++) {
            uint4 pk = ((const uint4*)he)[lane + 64 * c];
            unsigned int vs[4] = {pk.x, pk.y, pk.z, pk.w};
            #pragma unroll
            for (int e = 0; e < 4; e++) {
                float lo = __uint_as_float(vs[e] << 16);
                float hi = __uint_as_float(vs[e] & 0xFFFF0000u);
                num += uw[c * 8 + 2 * e] * lo + uw[c * 8 + 2 * e + 1] * hi;
                nrm += u2[c * 8 + 2 * e] * lo * lo + u2[c * 8 + 2 * e + 1] * hi * hi;
            }
        }
        #pragma unroll
        for (int off = 32; off > 0; off >>= 1) {
            num += __shfl_down(num, off);
            nrm += __shfl_down(nrm, off);
        }
        if (lane == 0)
            sw[h] = num / fmaxf(sqrtf(nrm), 1e-12f) + batt[0];
    }
    __syncthreads();
    if (tid < 64) {
        int h = lane & 31;
        bool v = (h <= q);
        float s = v ? sw[h] : -1e30f;
        float mx = s;
        #pragma unroll
        for (int off = 16; off > 0; off >>= 1)
            mx = fmaxf(mx, __shfl_xor(mx, off));
        float e = v ? expf(s - mx) : 0.f;
        float zs = e;
        #pragma unroll
        for (int off = 16; off > 0; off >>= 1)
            zs += __shfl_xor(zs, off);
        if (v && lane < 32) swn[h] = e / zs;
    }
    __syncthreads();
    const float4* hb = (const float4*)(hist + (size_t)b * ROUNDS * IN_DIM);
    float4* ob = (float4*)(out + (size_t)(b * ROUNDS + q) * IN_DIM);
    #pragma unroll
    for (int d0 = 0; d0 < 2; d0++) {
        int d = tid + d0 * 256;          // < 512 float4s
        float4 a = {0.f, 0.f, 0.f, 0.f};
        for (int h = 0; h <= q; h++) {
            float w = swn[h];
            float4 x = hb[h * 512 + d];
            a.x += w * x.x; a.y += w * x.y; a.z += w * x.z; a.w += w * x.w;
        }
        ob[d] = a;
    }
}

extern "C" void kernel_launch(void* const* d_in, const int* in_sizes, int n_in,
                              void* d_out, int out_size, void* d_ws, size_t ws_size,
                              hipStream_t stream) {
    const float* hist = (const float*)d_in[0];
    const float* ques = (const float*)d_in[1];
    const float* Why  = (const float*)d_in[2];
    const float* bhy  = (const float*)d_in[3];
    const float* Whg  = (const float*)d_in[4];
    const float* bhg  = (const float*)d_in[5];
    const float* Wqy  = (const float*)d_in[6];
    const float* bqy  = (const float*)d_in[7];
    const float* Wqg  = (const float*)d_in[8];
    const float* bqg  = (const float*)d_in[9];
    const float* watt = (const float*)d_in[10];
    const float* batt = (const float*)d_in[11];
    float* out = (float*)d_out;

    // workspace (~42 MB)
    char* w = (char*)d_ws;
    u16* Xh  = (u16*)w;                               // [2048,2048] bf16
    u16* Xq  = Xh  + (size_t)BROWS * IN_DIM;
    u16* WtH = Xq  + (size_t)BROWS * IN_DIM;          // [2048,2048] bf16 fused-interleaved
    u16* WtQ = WtH + (size_t)IN_DIM * IN_DIM;
    u16* Eh  = WtQ + (size_t)IN_DIM * IN_DIM;         // [2048,1024] bf16
    u16* Eq  = Eh  + (size_t)BROWS * H_DIM;

    prep<<<5120, 256, 0, stream>>>(hist, ques, Xh, Xq, Why, Whg, Wqy, Wqg, WtH, WtQ);
    gemm_act<<<256, 512, 0, stream>>>(Xh, Xq, WtH, WtQ, bhy, bhg, bqy, bqg, Eh, Eq);
    score_feat<<<2048, 256, 0, stream>>>(Eh, Eq, hist, watt, batt, out);
}